// Round 6
// baseline (392.629 us; speedup 1.0000x reference)
//
#include <hip/hip_runtime.h>
#include <hip/hip_bf16.h>
#include <cstdint>
#include <cstddef>

// Problem constants
#define BB 4
#define SS 2048
#define DD 1024
#define HH 16
#define HDD 64

typedef __bf16 bf16_t;
typedef __bf16 bf16x8 __attribute__((ext_vector_type(8)));
typedef float f32x4 __attribute__((ext_vector_type(4)));

__device__ __forceinline__ unsigned short f2bf(float f) {
    unsigned u = __float_as_uint(f);
    unsigned r = (u + 0x7FFFu + ((u >> 16) & 1u)) >> 16;
    return (unsigned short)r;
}
__device__ __forceinline__ bf16_t f2bf16(float f) {
    return __builtin_bit_cast(bf16_t, f2bf(f));
}
__device__ __forceinline__ bf16x8 cvt8(float4 a, float4 b) {
    bf16x8 r;
    r[0] = f2bf16(a.x); r[1] = f2bf16(a.y);
    r[2] = f2bf16(a.z); r[3] = f2bf16(a.w);
    r[4] = f2bf16(b.x); r[5] = f2bf16(b.y);
    r[6] = f2bf16(b.z); r[7] = f2bf16(b.w);
    return r;
}

// async global->LDS, 16B per lane; LDS dest = wave-uniform base + lane*16
#define GLL16(gp, lp)                                                          \
    __builtin_amdgcn_global_load_lds(                                          \
        (const __attribute__((address_space(1))) void*)(gp),                   \
        (__attribute__((address_space(3))) void*)(lp), 16, 0, 0)

// padded stride for attn LDS tiles (72 elem = 144 B: 16B-aligned rows,
// 2-way max bank aliasing on b128 reads / packed b32 writes = free)
#define LSTR 72

// ---------------------------------------------------------------------------
// fp32 -> bf16 converters (memory-bound, one-shot)
// ---------------------------------------------------------------------------
__global__ __launch_bounds__(256) void cvt1(const float* __restrict__ in,
                                            bf16_t* __restrict__ out) {
    size_t i = (size_t)blockIdx.x * 256 + threadIdx.x;
    const float4* p = (const float4*)in + i * 2;
    *(bf16x8*)(out + i * 8) = cvt8(p[0], p[1]);
}
__global__ __launch_bounds__(256) void cvt4(
    const float* __restrict__ w0, const float* __restrict__ w1,
    const float* __restrict__ w2, const float* __restrict__ w3,
    bf16_t* __restrict__ o0, bf16_t* __restrict__ o1,
    bf16_t* __restrict__ o2, bf16_t* __restrict__ o3) {
    const float* in = blockIdx.y == 0 ? w0 : blockIdx.y == 1 ? w1
                    : blockIdx.y == 2 ? w2 : w3;
    bf16_t* out = blockIdx.y == 0 ? o0 : blockIdx.y == 1 ? o1
                : blockIdx.y == 2 ? o2 : o3;
    size_t i = (size_t)blockIdx.x * 256 + threadIdx.x;
    const float4* p = (const float4*)in + i * 2;
    *(bf16x8*)(out + i * 8) = cvt8(p[0], p[1]);
}

// ---------------------------------------------------------------------------
// C(MxN) = A(MxK) @ W^T, all-bf16 inputs, fp32 acc. M=8192, N=K=1024.
// m97 pattern: global_load_lds width-16 staging, stride-64 LDS (no pad).
// MODE 0 (ROPE): apply RoPE, write bf16 (B,H,S,HD)
// MODE 1 (VT)  : write bf16 transposed (B,H,HD,S)   [fused V transpose]
// MODE 2 (OF32): write fp32 row-major (final output)
// ---------------------------------------------------------------------------
template <int MODE>
__global__ __launch_bounds__(256, 2) void gemm_bt(
    const bf16_t* __restrict__ A, const bf16_t* __restrict__ W,
    void* __restrict__ Cv,
    const float* __restrict__ fcos, const float* __restrict__ fsin)
{
    constexpr int K = 1024, N = 1024;
    __shared__ alignas(16) bf16_t lA[128 * 64];
    __shared__ alignas(16) bf16_t lB[128 * 64];

    const int tid  = threadIdx.x;
    const int w    = tid >> 6;
    const int lane = tid & 63;
    const int quad = lane >> 4;
    const int l16  = lane & 15;
    const int wm   = w >> 1;
    const int wn   = w & 1;
    const int m0   = blockIdx.y * 128;
    const int n0   = blockIdx.x * 128;

    f32x4 acc[4][4];
#pragma unroll
    for (int i = 0; i < 4; i++)
#pragma unroll
        for (int j = 0; j < 4; j++) acc[i][j] = (f32x4){0.f, 0.f, 0.f, 0.f};

    const int srow8 = lane >> 3;  // row within an 8-row GLL group
    const int slot  = lane & 7;   // 16B chunk within the 128B row

    for (int k0 = 0; k0 < K; k0 += 64) {
        // each wave stages 32 rows of A and of W via 4+4 GLL16
#pragma unroll
        for (int i = 0; i < 4; ++i) {
            int row = w * 32 + i * 8;
            GLL16(A + (size_t)(m0 + row + srow8) * K + k0 + slot * 8,
                  &lA[row * 64]);
            GLL16(W + (size_t)(n0 + row + srow8) * K + k0 + slot * 8,
                  &lB[row * 64]);
        }
        __syncthreads();
#pragma unroll
        for (int kk = 0; kk < 2; ++kk) {
            bf16x8 af[4], bfr[4];
#pragma unroll
            for (int mt = 0; mt < 4; ++mt)
                af[mt] = *(const bf16x8*)
                    &lA[(wm * 64 + mt * 16 + l16) * 64 + (kk * 4 + quad) * 8];
#pragma unroll
            for (int nt = 0; nt < 4; ++nt)
                bfr[nt] = *(const bf16x8*)
                    &lB[(wn * 64 + nt * 16 + l16) * 64 + (kk * 4 + quad) * 8];
#pragma unroll
            for (int mt = 0; mt < 4; ++mt)
#pragma unroll
                for (int nt = 0; nt < 4; ++nt)
                    acc[mt][nt] = __builtin_amdgcn_mfma_f32_16x16x32_bf16(
                        af[mt], bfr[nt], acc[mt][nt], 0, 0, 0);
        }
        __syncthreads();
    }

    if (MODE == 0) {
        unsigned short* Cu = (unsigned short*)Cv;
#pragma unroll
        for (int mt = 0; mt < 4; ++mt) {
#pragma unroll
            for (int nt = 0; nt < 4; ++nt) {
                int col  = n0 + wn * 64 + nt * 16 + l16;
                int h    = col >> 6;
                int d    = col & 63;
                int pidx = d >> 1;
                bool even = (col & 1) == 0;
#pragma unroll
                for (int r = 0; r < 4; ++r) {
                    int m = m0 + wm * 64 + mt * 16 + quad * 4 + r;
                    int b = m >> 11;   // / S
                    int s = m & 2047;  // % S
                    float v  = acc[mt][nt][r];
                    float p  = __shfl_xor(v, 1);
                    float c  = fcos[s * 32 + pidx];
                    float sn = fsin[s * 32 + pidx];
                    float o  = even ? (v * c - p * sn) : (p * sn + v * c);
                    Cu[(size_t)((b * HH + h) * SS + s) * HDD + d] = f2bf(o);
                }
            }
        }
    } else if (MODE == 1) {
        unsigned short* Cu = (unsigned short*)Cv;
#pragma unroll
        for (int mt = 0; mt < 4; ++mt) {
#pragma unroll
            for (int nt = 0; nt < 4; ++nt) {
                int col = n0 + wn * 64 + nt * 16 + l16;
                int h = col >> 6, d = col & 63;
#pragma unroll
                for (int r = 0; r < 4; ++r) {
                    int m = m0 + wm * 64 + mt * 16 + quad * 4 + r;
                    int b = m >> 11, s = m & 2047;
                    Cu[(size_t)((b * HH + h) * HDD + d) * SS + s] =
                        f2bf(acc[mt][nt][r]);
                }
            }
        }
    } else {
        float* Cf = (float*)Cv;
#pragma unroll
        for (int mt = 0; mt < 4; ++mt) {
            int mrow = m0 + wm * 64 + mt * 16 + quad * 4;
#pragma unroll
            for (int nt = 0; nt < 4; ++nt) {
                int col = n0 + wn * 64 + nt * 16 + l16;
#pragma unroll
                for (int r = 0; r < 4; ++r)
                    Cf[(size_t)(mrow + r) * N + col] = acc[mt][nt][r];
            }
        }
    }
}

// ---------------------------------------------------------------------------
// Flash attention v2: Q,K (B,H,S,HD) bf16, Vt (B,H,HD,S) bf16, O (B,S,D).
// Block covers TWO paired 128-row q-tiles (qtb, 15-qtb): every block does
// exactly 34 k-iterations -> perfect load balance. 4 waves, 32 q-rows/wave.
// Per wave-iter: 32 MFMA / 20 ds_read_b128; P-writes pair-packed b32.
// ---------------------------------------------------------------------------
__global__ __launch_bounds__(256, 4) void attn(
    const bf16_t* __restrict__ Q, const bf16_t* __restrict__ Kt,
    const bf16_t* __restrict__ Vt, bf16_t* __restrict__ O)
{
    const int bh   = blockIdx.y;
    const int tid  = threadIdx.x;
    const int w    = tid >> 6;
    const int lane = tid & 63;
    const int quad = lane >> 4;
    const int l16  = lane & 15;

    __shared__ alignas(16) bf16_t lK[64 * LSTR];
    __shared__ alignas(16) bf16_t lV[64 * LSTR];
    __shared__ alignas(16) bf16_t lP[128 * LSTR];

    const float sscale = 0.125f * 1.44269504088896f;  // 1/sqrt(64)*log2(e)
    const int srow = tid >> 2;   // 0..63 staging row
    const int sc0  = tid & 3;    // staging chunk base
    const int b = bh >> 4, h = bh & 15;
    unsigned short* Ou = (unsigned short*)O;

    for (int half = 0; half < 2; ++half) {
        const int qtb = half ? 15 - (int)blockIdx.x : (int)blockIdx.x;
        const int q0  = qtb * 128;
        const int nkb = 2 * qtb + 2;

        // Q fragments: 2 q-subtiles x 2 k-halves
        bf16x8 qf[2][2];
#pragma unroll
        for (int qs = 0; qs < 2; ++qs) {
            const bf16_t* qb = Q +
                (size_t)(bh * SS + q0 + w * 32 + qs * 16 + l16) * HDD + quad * 8;
            qf[qs][0] = *(const bf16x8*)(qb);
            qf[qs][1] = *(const bf16x8*)(qb + 32);
        }

        f32x4 o[2][4];
        float psum[2][4];
#pragma unroll
        for (int qs = 0; qs < 2; ++qs)
#pragma unroll
            for (int nt = 0; nt < 4; ++nt) {
                o[qs][nt] = (f32x4){0.f, 0.f, 0.f, 0.f};
                psum[qs][nt] = 0.f;  // reuse [nt] slot as r-index container
            }
        float ps[2][4] = {{0.f,0.f,0.f,0.f},{0.f,0.f,0.f,0.f}};

        // prologue: prefetch k-block 0
        bf16x8 kreg[2], vreg[2];
#pragma unroll
        for (int i = 0; i < 2; ++i) {
            int ch = sc0 + 4 * i;
            kreg[i] = *(const bf16x8*)&Kt[(size_t)(bh * SS + srow) * HDD + ch * 8];
            vreg[i] = *(const bf16x8*)&Vt[(size_t)(bh * HDD + srow) * SS + ch * 8];
        }

        for (int ib = 0; ib < nkb; ++ib) {
#pragma unroll
            for (int i = 0; i < 2; ++i) {
                int ch = sc0 + 4 * i;
                *(bf16x8*)&lK[srow * LSTR + ch * 8] = kreg[i];
                *(bf16x8*)&lV[srow * LSTR + ch * 8] = vreg[i];
            }
            __syncthreads();

            if (ib + 1 < nkb) {
                int kb = (ib + 1) * 64;
#pragma unroll
                for (int i = 0; i < 2; ++i) {
                    int ch = sc0 + 4 * i;
                    kreg[i] = *(const bf16x8*)
                        &Kt[(size_t)(bh * SS + kb + srow) * HDD + ch * 8];
                    vreg[i] = *(const bf16x8*)
                        &Vt[(size_t)(bh * HDD + srow) * SS + kb + ch * 8];
                }
            }

            const bool diag = (ib >= nkb - 2);
            // scores + exp + packed P write, tile by tile
#pragma unroll
            for (int nt = 0; nt < 4; ++nt) {
                bf16x8 kf0 = *(const bf16x8*)
                    &lK[(nt * 16 + l16) * LSTR + quad * 8];
                bf16x8 kf1 = *(const bf16x8*)
                    &lK[(nt * 16 + l16) * LSTR + 32 + quad * 8];
                int colg = ib * 64 + nt * 16 + l16;
#pragma unroll
                for (int qs = 0; qs < 2; ++qs) {
                    f32x4 s = (f32x4){0.f, 0.f, 0.f, 0.f};
                    s = __builtin_amdgcn_mfma_f32_16x16x32_bf16(qf[qs][0], kf0, s, 0, 0, 0);
                    s = __builtin_amdgcn_mfma_f32_16x16x32_bf16(qf[qs][1], kf1, s, 0, 0, 0);
                    int rbase = q0 + w * 32 + qs * 16 + quad * 4;
#pragma unroll
                    for (int r = 0; r < 4; ++r) {
                        float sv = s[r];
                        if (diag && colg > rbase + r) sv = -1e30f;
                        float pv = exp2f(sv * sscale);
                        ps[qs][r] += pv;
                        float partner = __shfl_xor(pv, 1);
                        if ((lane & 1) == 0) {
                            unsigned pk = (unsigned)f2bf(pv) |
                                          ((unsigned)f2bf(partner) << 16);
                            int row = w * 32 + qs * 16 + quad * 4 + r;
                            *(unsigned*)&lP[row * LSTR + nt * 16 + l16] = pk;
                        }
                    }
                }
            }

            // PV: O += P @ V  (lP wave-private; per-wave DS ops in-order)
#pragma unroll
            for (int kk = 0; kk < 2; ++kk) {
                bf16x8 pf[2];
#pragma unroll
                for (int qs = 0; qs < 2; ++qs)
                    pf[qs] = *(const bf16x8*)
                        &lP[(w * 32 + qs * 16 + l16) * LSTR + kk * 32 + quad * 8];
#pragma unroll
                for (int nt = 0; nt < 4; ++nt) {
                    bf16x8 vf = *(const bf16x8*)
                        &lV[(nt * 16 + l16) * LSTR + kk * 32 + quad * 8];
#pragma unroll
                    for (int qs = 0; qs < 2; ++qs)
                        o[qs][nt] = __builtin_amdgcn_mfma_f32_16x16x32_bf16(
                            pf[qs], vf, o[qs][nt], 0, 0, 0);
                }
            }
            __syncthreads();  // protect lK/lV before next staging
        }

        // epilogue: cross-lane row-sum reduce, O/l, write bf16 (B,S,D)
#pragma unroll
        for (int qs = 0; qs < 2; ++qs) {
            float lr[4];
#pragma unroll
            for (int r = 0; r < 4; ++r) {
                float v = ps[qs][r];
                v += __shfl_xor(v, 1);
                v += __shfl_xor(v, 2);
                v += __shfl_xor(v, 4);
                v += __shfl_xor(v, 8);
                lr[r] = v;
            }
#pragma unroll
            for (int nt = 0; nt < 4; ++nt) {
                int d = nt * 16 + l16;
#pragma unroll
                for (int r = 0; r < 4; ++r) {
                    int s = q0 + w * 32 + qs * 16 + quad * 4 + r;
                    float v = o[qs][nt][r] / lr[r];
                    Ou[(size_t)(b * SS + s) * DD + h * HDD + d] = f2bf(v);
                }
            }
        }
    }
}

// ---------------------------------------------------------------------------
// Buffer plan.  TSZ = B*S*D bf16 = 16 MiB; WSZ = D*D bf16 = 2 MiB.
//   d_out (32 MiB fp32): [0,TSZ) = xb, [TSZ,2*TSZ) = Vt — both dead before
//     the final GEMM overwrites d_out (it reads only Ob, wb3).
//   ws: Qb | Kb | Ob | wb0..3 = 56 MiB.
// ---------------------------------------------------------------------------
extern "C" void kernel_launch(void* const* d_in, const int* in_sizes, int n_in,
                              void* d_out, int out_size, void* d_ws,
                              size_t ws_size, hipStream_t stream)
{
    const float* x    = (const float*)d_in[0];
    const float* fcos = (const float*)d_in[1];
    const float* fsin = (const float*)d_in[2];
    const float* wq   = (const float*)d_in[3];
    const float* wk   = (const float*)d_in[4];
    const float* wv   = (const float*)d_in[5];
    const float* wo   = (const float*)d_in[6];

    char* ws = (char*)d_ws;
    const size_t TSZ = (size_t)BB * SS * DD * sizeof(bf16_t);  // 16 MiB
    const size_t WSZ = (size_t)DD * DD * sizeof(bf16_t);       // 2 MiB
    bf16_t* Qb  = (bf16_t*)(ws);
    bf16_t* Kb  = (bf16_t*)(ws + TSZ);
    bf16_t* Ob  = (bf16_t*)(ws + 2 * TSZ);
    bf16_t* wb0 = (bf16_t*)(ws + 3 * TSZ);
    bf16_t* wb1 = (bf16_t*)(ws + 3 * TSZ + WSZ);
    bf16_t* wb2 = (bf16_t*)(ws + 3 * TSZ + 2 * WSZ);
    bf16_t* wb3 = (bf16_t*)(ws + 3 * TSZ + 3 * WSZ);
    bf16_t* xb  = (bf16_t*)d_out;
    bf16_t* Vt  = (bf16_t*)((char*)d_out + TSZ);

    dim3 bb(256);
    cvt1<<<dim3(4096), bb, 0, stream>>>(x, xb);
    cvt4<<<dim3(512, 4), bb, 0, stream>>>(wq, wk, wv, wo, wb0, wb1, wb2, wb3);

    dim3 gg(8, 64);
    gemm_bt<0><<<gg, bb, 0, stream>>>(xb, wb0, Qb, fcos, fsin);
    gemm_bt<0><<<gg, bb, 0, stream>>>(xb, wb1, Kb, fcos, fsin);
    gemm_bt<1><<<gg, bb, 0, stream>>>(xb, wb2, Vt, fcos, fsin);
    attn<<<dim3(8, 64), bb, 0, stream>>>(Qb, Kb, Vt, Ob);
    gemm_bt<2><<<gg, bb, 0, stream>>>(Ob, wb3, d_out, fcos, fsin);
}

// Round 7
// 345.551 us; speedup vs baseline: 1.1362x; 1.1362x over previous
//
#include <hip/hip_runtime.h>
#include <hip/hip_bf16.h>
#include <cstdint>
#include <cstddef>

// Problem constants
#define BB 4
#define SS 2048
#define DD 1024
#define HH 16
#define HDD 64

typedef __bf16 bf16_t;
typedef __bf16 bf16x8 __attribute__((ext_vector_type(8)));
typedef float f32x4 __attribute__((ext_vector_type(4)));

__device__ __forceinline__ unsigned short f2bf(float f) {
    unsigned u = __float_as_uint(f);
    unsigned r = (u + 0x7FFFu + ((u >> 16) & 1u)) >> 16;
    return (unsigned short)r;
}
__device__ __forceinline__ bf16_t f2bf16(float f) {
    return __builtin_bit_cast(bf16_t, f2bf(f));
}
__device__ __forceinline__ bf16x8 cvt8(float4 a, float4 b) {
    bf16x8 r;
    r[0] = f2bf16(a.x); r[1] = f2bf16(a.y);
    r[2] = f2bf16(a.z); r[3] = f2bf16(a.w);
    r[4] = f2bf16(b.x); r[5] = f2bf16(b.y);
    r[6] = f2bf16(b.z); r[7] = f2bf16(b.w);
    return r;
}

// async global->LDS, 16B per lane; LDS dest = wave-uniform base + lane*16
#define GLL16(gp, lp)                                                          \
    __builtin_amdgcn_global_load_lds(                                          \
        (const __attribute__((address_space(1))) void*)(gp),                   \
        (__attribute__((address_space(3))) void*)(lp), 16, 0, 0)

// padded stride for attn P tile (72 elem = 144 B): 16B-aligned rows, <=2-way
// bank aliasing on both the packed b32 writes and the b128 reads (free).
#define LSTR 72

// ---------------------------------------------------------------------------
// fp32 -> bf16 converters (memory-bound, one-shot)
// ---------------------------------------------------------------------------
__global__ __launch_bounds__(256) void cvt1(const float* __restrict__ in,
                                            bf16_t* __restrict__ out) {
    size_t i = (size_t)blockIdx.x * 256 + threadIdx.x;
    const float4* p = (const float4*)in + i * 2;
    *(bf16x8*)(out + i * 8) = cvt8(p[0], p[1]);
}
__global__ __launch_bounds__(256) void cvt4(
    const float* __restrict__ w0, const float* __restrict__ w1,
    const float* __restrict__ w2, const float* __restrict__ w3,
    bf16_t* __restrict__ o0, bf16_t* __restrict__ o1,
    bf16_t* __restrict__ o2, bf16_t* __restrict__ o3) {
    const float* in = blockIdx.y == 0 ? w0 : blockIdx.y == 1 ? w1
                    : blockIdx.y == 2 ? w2 : w3;
    bf16_t* out = blockIdx.y == 0 ? o0 : blockIdx.y == 1 ? o1
                : blockIdx.y == 2 ? o2 : o3;
    size_t i = (size_t)blockIdx.x * 256 + threadIdx.x;
    const float4* p = (const float4*)in + i * 2;
    *(bf16x8*)(out + i * 8) = cvt8(p[0], p[1]);
}

// ---------------------------------------------------------------------------
// C(MxN) = A(MxK) @ W^T, all-bf16 inputs, fp32 acc. M=8192, N=K=1024.
// m97 pattern: global_load_lds width-16 staging, stride-64 LDS.
// MODE 0 (ROPE): apply RoPE, write bf16 (B,H,S,HD)
// MODE 1 (VT)  : write bf16 transposed (B,H,HD,S)   [fused V transpose]
// MODE 2 (OF32): write fp32 row-major (final output)
// ---------------------------------------------------------------------------
template <int MODE>
__global__ __launch_bounds__(256, 2) void gemm_bt(
    const bf16_t* __restrict__ A, const bf16_t* __restrict__ W,
    void* __restrict__ Cv,
    const float* __restrict__ fcos, const float* __restrict__ fsin)
{
    constexpr int K = 1024, N = 1024;
    __shared__ alignas(16) bf16_t lA[128 * 64];
    __shared__ alignas(16) bf16_t lB[128 * 64];

    const int tid  = threadIdx.x;
    const int w    = tid >> 6;
    const int lane = tid & 63;
    const int quad = lane >> 4;
    const int l16  = lane & 15;
    const int wm   = w >> 1;
    const int wn   = w & 1;
    const int m0   = blockIdx.y * 128;
    const int n0   = blockIdx.x * 128;

    f32x4 acc[4][4];
#pragma unroll
    for (int i = 0; i < 4; i++)
#pragma unroll
        for (int j = 0; j < 4; j++) acc[i][j] = (f32x4){0.f, 0.f, 0.f, 0.f};

    const int srow8 = lane >> 3;  // row within an 8-row GLL group
    const int slot  = lane & 7;   // 16B chunk within the 128B row

    for (int k0 = 0; k0 < K; k0 += 64) {
#pragma unroll
        for (int i = 0; i < 4; ++i) {
            int row = w * 32 + i * 8;
            GLL16(A + (size_t)(m0 + row + srow8) * K + k0 + slot * 8,
                  &lA[row * 64]);
            GLL16(W + (size_t)(n0 + row + srow8) * K + k0 + slot * 8,
                  &lB[row * 64]);
        }
        __syncthreads();
#pragma unroll
        for (int kk = 0; kk < 2; ++kk) {
            bf16x8 af[4], bfr[4];
#pragma unroll
            for (int mt = 0; mt < 4; ++mt)
                af[mt] = *(const bf16x8*)
                    &lA[(wm * 64 + mt * 16 + l16) * 64 + (kk * 4 + quad) * 8];
#pragma unroll
            for (int nt = 0; nt < 4; ++nt)
                bfr[nt] = *(const bf16x8*)
                    &lB[(wn * 64 + nt * 16 + l16) * 64 + (kk * 4 + quad) * 8];
#pragma unroll
            for (int mt = 0; mt < 4; ++mt)
#pragma unroll
                for (int nt = 0; nt < 4; ++nt)
                    acc[mt][nt] = __builtin_amdgcn_mfma_f32_16x16x32_bf16(
                        af[mt], bfr[nt], acc[mt][nt], 0, 0, 0);
        }
        __syncthreads();
    }

    if (MODE == 0) {
        unsigned short* Cu = (unsigned short*)Cv;
#pragma unroll
        for (int mt = 0; mt < 4; ++mt) {
#pragma unroll
            for (int nt = 0; nt < 4; ++nt) {
                int col  = n0 + wn * 64 + nt * 16 + l16;
                int h    = col >> 6;
                int d    = col & 63;
                int pidx = d >> 1;
                bool even = (col & 1) == 0;
#pragma unroll
                for (int r = 0; r < 4; ++r) {
                    int m = m0 + wm * 64 + mt * 16 + quad * 4 + r;
                    int b = m >> 11;   // / S
                    int s = m & 2047;  // % S
                    float v  = acc[mt][nt][r];
                    float p  = __shfl_xor(v, 1);
                    float c  = fcos[s * 32 + pidx];
                    float sn = fsin[s * 32 + pidx];
                    float o  = even ? (v * c - p * sn) : (p * sn + v * c);
                    Cu[(size_t)((b * HH + h) * SS + s) * HDD + d] = f2bf(o);
                }
            }
        }
    } else if (MODE == 1) {
        unsigned short* Cu = (unsigned short*)Cv;
#pragma unroll
        for (int mt = 0; mt < 4; ++mt) {
#pragma unroll
            for (int nt = 0; nt < 4; ++nt) {
                int col = n0 + wn * 64 + nt * 16 + l16;
                int h = col >> 6, d = col & 63;
#pragma unroll
                for (int r = 0; r < 4; ++r) {
                    int m = m0 + wm * 64 + mt * 16 + quad * 4 + r;
                    int b = m >> 11, s = m & 2047;
                    Cu[(size_t)((b * HH + h) * HDD + d) * SS + s] =
                        f2bf(acc[mt][nt][r]);
                }
            }
        }
    } else {
        float* Cf = (float*)Cv;
#pragma unroll
        for (int mt = 0; mt < 4; ++mt) {
            int mrow = m0 + wm * 64 + mt * 16 + quad * 4;
#pragma unroll
            for (int nt = 0; nt < 4; ++nt) {
                int col = n0 + wn * 64 + nt * 16 + l16;
#pragma unroll
                for (int r = 0; r < 4; ++r)
                    Cf[(size_t)(mrow + r) * N + col] = acc[mt][nt][r];
            }
        }
    }
}

// ---------------------------------------------------------------------------
// Flash attention v3 — barrier-free. Q,K (B,H,S,HD), Vt (B,H,HD,S), O (B,S,D).
// B-operand fragments of mfma_16x16x32 are lane-contiguous in K, and Kt/Vt
// store exactly those 8 elements contiguously -> load K/V fragments DIRECTLY
// from global (L2-served; XCD-affinity swizzle keeps per-XCD set ~4MB).
// Each wave owns paired 32-row q-tiles (t, 63-t): 33 k-iters, balanced,
// fully independent. Only LDS: wave-private P round-trip (no barriers).
// ---------------------------------------------------------------------------
__global__ __launch_bounds__(256, 2) void attn(
    const bf16_t* __restrict__ Q, const bf16_t* __restrict__ Kt,
    const bf16_t* __restrict__ Vt, bf16_t* __restrict__ O)
{
    const int tid  = threadIdx.x;
    const int w    = tid >> 6;
    const int lane = tid & 63;
    const int quad = lane >> 4;
    const int l16  = lane & 15;

    __shared__ alignas(16) bf16_t lP[4 * 32 * LSTR];  // 18 KiB, wave-private

    // XCD-affinity decode: all blocks of a given bh land on XCD bh&7.
    const int blk  = blockIdx.x;          // 0..511
    const int xcd  = blk & 7;
    const int rest = blk >> 3;            // 0..63
    const int g    = rest & 7;            // pair-group within bh
    const int bh   = ((rest >> 3) << 3) | xcd;
    const int pg   = g * 4 + w;           // 0..31 pair index

    const float sscale = 0.125f * 1.44269504088896f;  // 1/sqrt(64)*log2(e)
    const int b = bh >> 4, h = bh & 15;
    unsigned short* Ou = (unsigned short*)O;
    bf16_t* lpw = &lP[w * 32 * LSTR];
    const bf16_t* Kb = Kt + (size_t)bh * SS * HDD;
    const bf16_t* Vb = Vt + (size_t)bh * HDD * SS;

    for (int half = 0; half < 2; ++half) {
        const int t   = half ? 63 - pg : pg;   // 32-row tile index
        const int q0  = t * 32;
        const int nkb = (t >> 1) + 1;

        // Q fragments: 2 subtiles x 2 k-chunks, straight from global
        bf16x8 qf[2][2];
#pragma unroll
        for (int qs = 0; qs < 2; ++qs) {
            const bf16_t* qp =
                Q + (size_t)(bh * SS + q0 + qs * 16 + l16) * HDD + quad * 8;
            qf[qs][0] = *(const bf16x8*)(qp);
            qf[qs][1] = *(const bf16x8*)(qp + 32);
        }

        f32x4 o[2][4];
        float ps[2][4];
#pragma unroll
        for (int qs = 0; qs < 2; ++qs)
#pragma unroll
            for (int i = 0; i < 4; ++i) {
                o[qs][i] = (f32x4){0.f, 0.f, 0.f, 0.f};
                ps[qs][i] = 0.f;
            }

        for (int ib = 0; ib < nkb; ++ib) {
            const int kb = ib * 64;
            const bool diag = (ib == nkb - 1);

            // K fragments (B-operand), direct global loads
            bf16x8 kf[4][2];
#pragma unroll
            for (int nt = 0; nt < 4; ++nt) {
                const bf16_t* kp =
                    Kb + (size_t)(kb + nt * 16 + l16) * HDD + quad * 8;
                kf[nt][0] = *(const bf16x8*)(kp);
                kf[nt][1] = *(const bf16x8*)(kp + 32);
            }
            // V fragments (B-operand), direct global loads (independent of P
            // -> compiler can issue them early alongside the score MFMAs)
            bf16x8 vf[2][4];
#pragma unroll
            for (int kk = 0; kk < 2; ++kk)
#pragma unroll
                for (int nt = 0; nt < 4; ++nt)
                    vf[kk][nt] = *(const bf16x8*)
                        &Vb[(size_t)(nt * 16 + l16) * SS + kb + kk * 32 + quad * 8];

            // scores + exp + packed P write
#pragma unroll
            for (int nt = 0; nt < 4; ++nt) {
                int colg = kb + nt * 16 + l16;
#pragma unroll
                for (int qs = 0; qs < 2; ++qs) {
                    f32x4 s = (f32x4){0.f, 0.f, 0.f, 0.f};
                    s = __builtin_amdgcn_mfma_f32_16x16x32_bf16(
                        qf[qs][0], kf[nt][0], s, 0, 0, 0);
                    s = __builtin_amdgcn_mfma_f32_16x16x32_bf16(
                        qf[qs][1], kf[nt][1], s, 0, 0, 0);
                    int rbase = q0 + qs * 16 + quad * 4;
#pragma unroll
                    for (int r = 0; r < 4; ++r) {
                        float sv = s[r];
                        if (diag && colg > rbase + r) sv = -1e30f;
                        float pv = exp2f(sv * sscale);
                        ps[qs][r] += pv;
                        float partner = __shfl_xor(pv, 1);
                        if ((lane & 1) == 0) {
                            // truncating bf16 pack: lo=hi16(pv), hi=hi16(partner)
                            unsigned pk = (__float_as_uint(pv) >> 16) |
                                          (__float_as_uint(partner) & 0xFFFF0000u);
                            int row = qs * 16 + quad * 4 + r;
                            *(unsigned*)&lpw[row * LSTR + nt * 16 + l16] = pk;
                        }
                    }
                }
            }

            // PV: O += P @ V  (wave-private LDS RAW; per-wave DS in-order)
#pragma unroll
            for (int kk = 0; kk < 2; ++kk) {
                bf16x8 pf[2];
#pragma unroll
                for (int qs = 0; qs < 2; ++qs)
                    pf[qs] = *(const bf16x8*)
                        &lpw[(qs * 16 + l16) * LSTR + kk * 32 + quad * 8];
#pragma unroll
                for (int nt = 0; nt < 4; ++nt)
#pragma unroll
                    for (int qs = 0; qs < 2; ++qs)
                        o[qs][nt] = __builtin_amdgcn_mfma_f32_16x16x32_bf16(
                            pf[qs], vf[kk][nt], o[qs][nt], 0, 0, 0);
            }
        }

        // epilogue: cross-lane row-sum reduce, O/l, write bf16 (B,S,D)
#pragma unroll
        for (int qs = 0; qs < 2; ++qs) {
            float lr[4];
#pragma unroll
            for (int r = 0; r < 4; ++r) {
                float v = ps[qs][r];
                v += __shfl_xor(v, 1);
                v += __shfl_xor(v, 2);
                v += __shfl_xor(v, 4);
                v += __shfl_xor(v, 8);
                lr[r] = v;
            }
#pragma unroll
            for (int nt = 0; nt < 4; ++nt) {
                int d = nt * 16 + l16;
#pragma unroll
                for (int r = 0; r < 4; ++r) {
                    int s = q0 + qs * 16 + quad * 4 + r;
                    float v = o[qs][nt][r] / lr[r];
                    Ou[(size_t)(b * SS + s) * DD + h * HDD + d] = f2bf(v);
                }
            }
        }
    }
}

// ---------------------------------------------------------------------------
// Buffer plan.  TSZ = B*S*D bf16 = 16 MiB; WSZ = D*D bf16 = 2 MiB.
//   d_out (32 MiB fp32): [0,TSZ) = xb, [TSZ,2*TSZ) = Vt — both dead before
//     the final GEMM overwrites d_out (it reads only Ob, wb3).
//   ws: Qb | Kb | Ob | wb0..3 = 56 MiB.
// ---------------------------------------------------------------------------
extern "C" void kernel_launch(void* const* d_in, const int* in_sizes, int n_in,
                              void* d_out, int out_size, void* d_ws,
                              size_t ws_size, hipStream_t stream)
{
    const float* x    = (const float*)d_in[0];
    const float* fcos = (const float*)d_in[1];
    const float* fsin = (const float*)d_in[2];
    const float* wq   = (const float*)d_in[3];
    const float* wk   = (const float*)d_in[4];
    const float* wv   = (const float*)d_in[5];
    const float* wo   = (const float*)d_in[6];

    char* ws = (char*)d_ws;
    const size_t TSZ = (size_t)BB * SS * DD * sizeof(bf16_t);  // 16 MiB
    const size_t WSZ = (size_t)DD * DD * sizeof(bf16_t);       // 2 MiB
    bf16_t* Qb  = (bf16_t*)(ws);
    bf16_t* Kb  = (bf16_t*)(ws + TSZ);
    bf16_t* Ob  = (bf16_t*)(ws + 2 * TSZ);
    bf16_t* wb0 = (bf16_t*)(ws + 3 * TSZ);
    bf16_t* wb1 = (bf16_t*)(ws + 3 * TSZ + WSZ);
    bf16_t* wb2 = (bf16_t*)(ws + 3 * TSZ + 2 * WSZ);
    bf16_t* wb3 = (bf16_t*)(ws + 3 * TSZ + 3 * WSZ);
    bf16_t* xb  = (bf16_t*)d_out;
    bf16_t* Vt  = (bf16_t*)((char*)d_out + TSZ);

    dim3 bb(256);
    cvt1<<<dim3(4096), bb, 0, stream>>>(x, xb);
    cvt4<<<dim3(512, 4), bb, 0, stream>>>(wq, wk, wv, wo, wb0, wb1, wb2, wb3);

    dim3 gg(8, 64);
    gemm_bt<0><<<gg, bb, 0, stream>>>(xb, wb0, Qb, fcos, fsin);
    gemm_bt<0><<<gg, bb, 0, stream>>>(xb, wb1, Kb, fcos, fsin);
    gemm_bt<1><<<gg, bb, 0, stream>>>(xb, wb2, Vt, fcos, fsin);
    attn<<<dim3(512), bb, 0, stream>>>(Qb, Kb, Vt, Ob);
    gemm_bt<2><<<gg, bb, 0, stream>>>(Ob, wb3, d_out, fcos, fsin);
}